// Round 1
// baseline (414.173 us; speedup 1.0000x reference)
//
#include <hip/hip_runtime.h>
#include <stdint.h>

#define D_MODEL 1024
#define SEQ 2048
#define BATCH 4
#define NH 16
#define DK 64

typedef float f32x4 __attribute__((ext_vector_type(4)));
typedef __bf16 bf16x8 __attribute__((ext_vector_type(8)));
typedef unsigned short us4v __attribute__((ext_vector_type(4)));

__device__ __forceinline__ unsigned short f2bf(float f) {
  union { float f; unsigned u; } x; x.f = f;
  unsigned r = x.u + 0x7FFFu + ((x.u >> 16) & 1u);  // RNE
  return (unsigned short)(r >> 16);
}

// async global->LDS, 16B per lane. LDS dest is wave-uniform base + lane*16,
// so LDS layout stays linear; swizzling is done on the GLOBAL source address.
__device__ __forceinline__ void gll16(const void* g, void* l) {
  __builtin_amdgcn_global_load_lds(
      (__attribute__((address_space(1))) void*)g,
      (__attribute__((address_space(3))) void*)l, 16, 0, 0);
}

// ---------------------------------------------------------------------------
// fp32 -> bf16 convert (vectorized float4 -> 4x bf16)
// ---------------------------------------------------------------------------
__global__ void cvtbf(const float* __restrict__ in, unsigned short* __restrict__ out, const int n) {
  const int t = blockIdx.x * blockDim.x + threadIdx.x;
  const int stride = gridDim.x * blockDim.x;
  for (int i = t * 4; i < n; i += stride * 4) {
    const float4 v = *(const float4*)&in[i];
    us4v o;
    o[0] = f2bf(v.x); o[1] = f2bf(v.y); o[2] = f2bf(v.z); o[3] = f2bf(v.w);
    *(us4v*)&out[i] = o;
  }
}

// ---------------------------------------------------------------------------
// weight transpose + convert: W[k][n] fp32 -> Wt[n][k] bf16   (1024x1024, x4)
// ---------------------------------------------------------------------------
__global__ void wtrans(const float* __restrict__ W0, const float* __restrict__ W1,
                       const float* __restrict__ W2, const float* __restrict__ W3,
                       unsigned short* __restrict__ T0, unsigned short* __restrict__ T1,
                       unsigned short* __restrict__ T2, unsigned short* __restrict__ T3) {
  __shared__ float t[32][33];
  const int z = blockIdx.z;
  const float* W = (z == 0) ? W0 : (z == 1) ? W1 : (z == 2) ? W2 : W3;
  unsigned short* T = (z == 0) ? T0 : (z == 1) ? T1 : (z == 2) ? T2 : T3;
  const int n0 = blockIdx.x * 32, k0 = blockIdx.y * 32;
  const int tx = threadIdx.x, ty = threadIdx.y;  // 32 x 8
#pragma unroll
  for (int i = 0; i < 4; ++i)
    t[ty + 8 * i][tx] = W[(size_t)(k0 + ty + 8 * i) * D_MODEL + n0 + tx];
  __syncthreads();
#pragma unroll
  for (int i = 0; i < 4; ++i)
    T[(size_t)(n0 + ty + 8 * i) * D_MODEL + k0 + tx] = f2bf(t[tx][ty + 8 * i]);
}

// ---------------------------------------------------------------------------
// bf16 GEMM: C[M=8192][N=1024] = A[M][K=1024] @ Wt[N][K]^T + bias
// 128x128 tile, BK=64, 4 waves (2x2 of 64x64), mfma_f32_16x16x32_bf16.
// XOR slot-swizzle (slot ^ (row&7)) applied on global source AND ds_read.
// mode 0: out bf16 [b,h,s,d]   (Q, K)
// mode 1: out bf16 [b,h,d,s]   (V transposed for attention PV B-operand)
// mode 2: out fp32 [m][n]      (final projection into d_out)
// ---------------------------------------------------------------------------
__global__ __launch_bounds__(256) void gemm128(
    const unsigned short* __restrict__ A, const unsigned short* __restrict__ Bt,
    const float* __restrict__ bias, unsigned short* __restrict__ outb,
    float* __restrict__ outf, const int mode) {
  __shared__ __align__(16) unsigned short Alds[128 * 64];
  __shared__ __align__(16) unsigned short Blds[128 * 64];
  const int tid = threadIdx.x;
  const int lane = tid & 63;
  const int w = tid >> 6;
  const int wr = w >> 1, wc = w & 1;
  const int m0 = blockIdx.y * 128, n0 = blockIdx.x * 128;
  const int srow = tid >> 3, sslot = tid & 7;

  f32x4 acc[4][4] = {};

  for (int kk = 0; kk < D_MODEL / 64; ++kk) {
    __syncthreads();  // protect LDS from previous iteration's readers
#pragma unroll
    for (int i = 0; i < 4; ++i) {
      const int r = srow + 32 * i;
      const int gc = kk * 64 + ((sslot ^ (r & 7)) << 3);
      gll16(A + (size_t)(m0 + r) * D_MODEL + gc, &Alds[tid * 8 + i * 2048]);
      gll16(Bt + (size_t)(n0 + r) * D_MODEL + gc, &Blds[tid * 8 + i * 2048]);
    }
    __syncthreads();  // compiler drains vmcnt(0) before barrier
#pragma unroll
    for (int kf = 0; kf < 2; ++kf) {
      const int sb = kf * 4 + (lane >> 4);
      bf16x8 a[4], b[4];
#pragma unroll
      for (int m = 0; m < 4; ++m) {
        const int row = wr * 64 + m * 16 + (lane & 15);
        a[m] = *(const bf16x8*)&Alds[row * 64 + ((sb ^ (row & 7)) << 3)];
      }
#pragma unroll
      for (int n = 0; n < 4; ++n) {
        const int row = wc * 64 + n * 16 + (lane & 15);
        b[n] = *(const bf16x8*)&Blds[row * 64 + ((sb ^ (row & 7)) << 3)];
      }
#pragma unroll
      for (int m = 0; m < 4; ++m)
#pragma unroll
        for (int n = 0; n < 4; ++n)
          acc[m][n] = __builtin_amdgcn_mfma_f32_16x16x32_bf16(a[m], b[n], acc[m][n], 0, 0, 0);
    }
  }

  // epilogue: C/D frag layout col = lane&15, row = (lane>>4)*4 + j  [m89]
#pragma unroll
  for (int m = 0; m < 4; ++m) {
    const int rb = m0 + wr * 64 + m * 16 + ((lane >> 4) << 2);
#pragma unroll
    for (int n = 0; n < 4; ++n) {
      const int col = n0 + wc * 64 + n * 16 + (lane & 15);
      const float bv = bias[col];
#pragma unroll
      for (int j = 0; j < 4; ++j) {
        const int row = rb + j;
        const float v = acc[m][n][j] + bv;
        if (mode == 2) {
          outf[(size_t)row * D_MODEL + col] = v;
        } else {
          const int b_ = row >> 11, s_ = row & (SEQ - 1);
          const int h_ = col >> 6, d_ = col & (DK - 1);
          size_t idx;
          if (mode == 0) idx = (((size_t)(b_ * NH + h_)) * SEQ + s_) * DK + d_;
          else           idx = (((size_t)(b_ * NH + h_)) * DK + d_) * SEQ + s_;
          outb[idx] = f2bf(v);
        }
      }
    }
  }
}

// ---------------------------------------------------------------------------
// causal flash attention. Block = (qt, bh): 64 q-rows, 4 waves x 16 rows.
// Q in registers; K [kv][d] and Vt [d][kv] staged in swizzled LDS per 64-kv tile.
// Online softmax with 16-lane shuffle reductions. Out: O bf16 [b*s][h*64+d].
// ---------------------------------------------------------------------------
__global__ __launch_bounds__(256) void attn64(
    const unsigned short* __restrict__ Q, const unsigned short* __restrict__ K,
    const unsigned short* __restrict__ Vt, unsigned short* __restrict__ O) {
  __shared__ __align__(16) unsigned short Klds[64 * 64];
  __shared__ __align__(16) unsigned short Vlds[64 * 64];
  __shared__ __align__(16) unsigned short Plds[4 * 16 * 64];

  const int tid = threadIdx.x, lane = tid & 63, w = tid >> 6;
  const int qt = blockIdx.x, bh = blockIdx.y;
  const int q0 = qt * 64;
  const size_t qkbase = (size_t)bh * SEQ * DK;
  const int srow = tid >> 3, sslot = tid & 7;

  // Q fragments: A-operand layout row=lane&15, k = (lane>>4)*8+e
  bf16x8 qf[2];
  {
    const int qrow = q0 + w * 16 + (lane & 15);
    const unsigned short* qp = Q + qkbase + (size_t)qrow * DK + ((lane >> 4) << 3);
    qf[0] = *(const bf16x8*)qp;
    qf[1] = *(const bf16x8*)(qp + 32);
  }

  float mrow[4] = {-3e38f, -3e38f, -3e38f, -3e38f};
  float lrow[4] = {0.f, 0.f, 0.f, 0.f};
  f32x4 oacc[4] = {};

  for (int jt = 0; jt <= qt; ++jt) {
    __syncthreads();
#pragma unroll
    for (int i = 0; i < 2; ++i) {
      const int r = srow + 32 * i;
      const int sc = (sslot ^ (r & 7)) << 3;
      gll16(K + qkbase + (size_t)(jt * 64 + r) * DK + sc, &Klds[tid * 8 + i * 2048]);
      gll16(Vt + ((size_t)bh * DK + r) * SEQ + jt * 64 + sc, &Vlds[tid * 8 + i * 2048]);
    }
    __syncthreads();

    // S = Q K^T : per-wave 16x64 strip
    f32x4 sa[4] = {};
#pragma unroll
    for (int kf = 0; kf < 2; ++kf) {
      const int sb = kf * 4 + (lane >> 4);
#pragma unroll
      for (int n = 0; n < 4; ++n) {
        const int row = n * 16 + (lane & 15);
        const bf16x8 bk = *(const bf16x8*)&Klds[row * 64 + ((sb ^ (row & 7)) << 3)];
        sa[n] = __builtin_amdgcn_mfma_f32_16x16x32_bf16(qf[kf], bk, sa[n], 0, 0, 0);
      }
    }

    const bool diag = (jt == qt);
    float p[4][4];
#pragma unroll
    for (int j = 0; j < 4; ++j) {
      const int qrow = q0 + w * 16 + ((lane >> 4) << 2) + j;
      float mx = -3e38f;
#pragma unroll
      for (int n = 0; n < 4; ++n) {
        float s = sa[n][j] * 0.125f;  // 1/sqrt(64)
        if (diag && (jt * 64 + n * 16 + (lane & 15)) > qrow) s = -3e38f;
        p[n][j] = s;
        mx = fmaxf(mx, s);
      }
#pragma unroll
      for (int dd = 1; dd < 16; dd <<= 1) mx = fmaxf(mx, __shfl_xor(mx, dd, 16));
      const float mnew = fmaxf(mrow[j], mx);
      const float alpha = exp2f((mrow[j] - mnew) * 1.44269504f);
      mrow[j] = mnew;
      float rs = 0.f;
#pragma unroll
      for (int n = 0; n < 4; ++n) {
        const float e = exp2f((p[n][j] - mnew) * 1.44269504f);
        p[n][j] = e;
        rs += e;
      }
#pragma unroll
      for (int dd = 1; dd < 16; dd <<= 1) rs += __shfl_xor(rs, dd, 16);
      lrow[j] = lrow[j] * alpha + rs;
#pragma unroll
      for (int dn = 0; dn < 4; ++dn) oacc[dn][j] *= alpha;
    }

    // P (C-frag layout) -> wave-private swizzled LDS -> A-frag layout
    unsigned short* pl = &Plds[w * 16 * 64];
#pragma unroll
    for (int n = 0; n < 4; ++n)
#pragma unroll
      for (int j = 0; j < 4; ++j) {
        const int row = ((lane >> 4) << 2) + j;
        const int col = n * 16 + (lane & 15);
        pl[row * 64 + (((col >> 3) ^ (row & 7)) << 3) + (col & 7)] = f2bf(p[n][j]);
      }
    // same-wave LDS ops are in-order; compiler inserts lgkmcnt before reuse

    // O += P @ V   (B-operand from Vt: row d = dn*16 + lane&15, contiguous kv)
#pragma unroll
    for (int kf = 0; kf < 2; ++kf) {
      const int sb = kf * 4 + (lane >> 4);
      const int prow = lane & 15;
      const bf16x8 pa = *(const bf16x8*)&pl[prow * 64 + ((sb ^ (prow & 7)) << 3)];
#pragma unroll
      for (int dn = 0; dn < 4; ++dn) {
        const int vrow = dn * 16 + (lane & 15);
        const bf16x8 bv = *(const bf16x8*)&Vlds[vrow * 64 + ((sb ^ (vrow & 7)) << 3)];
        oacc[dn] = __builtin_amdgcn_mfma_f32_16x16x32_bf16(pa, bv, oacc[dn], 0, 0, 0);
      }
    }
  }

  const int b_ = bh >> 4, h_ = bh & (NH - 1);
#pragma unroll
  for (int dn = 0; dn < 4; ++dn) {
    const int col = h_ * DK + dn * 16 + (lane & 15);
#pragma unroll
    for (int j = 0; j < 4; ++j) {
      const int srw = q0 + w * 16 + ((lane >> 4) << 2) + j;
      O[((size_t)(b_ * SEQ + srw)) * D_MODEL + col] = f2bf(oacc[dn][j] / lrow[j]);
    }
  }
}

// ---------------------------------------------------------------------------
extern "C" void kernel_launch(void* const* d_in, const int* in_sizes, int n_in,
                              void* d_out, int out_size, void* d_ws, size_t ws_size,
                              hipStream_t stream) {
  const float* ctx = (const float*)d_in[0];
  const float* val = (const float*)d_in[1];
  // d_in[2] = mask: statically causal triu(k=1); handled analytically.
  const float* Wq = (const float*)d_in[3];
  const float* bq = (const float*)d_in[4];
  const float* Wk = (const float*)d_in[5];
  const float* bk = (const float*)d_in[6];
  const float* Wv = (const float*)d_in[7];
  const float* bv = (const float*)d_in[8];
  const float* Wo = (const float*)d_in[9];
  const float* bo = (const float*)d_in[10];

  unsigned short* ws = (unsigned short*)d_ws;
  const size_t XSZ = (size_t)BATCH * SEQ * D_MODEL;  // 8388608
  const size_t WSZ = (size_t)D_MODEL * D_MODEL;      // 1048576
  // total ws use: 6*XSZ + 4*WSZ ushorts = ~109 MB
  unsigned short* Xc  = ws;
  unsigned short* Xv  = Xc + XSZ;
  unsigned short* Wqt = Xv + XSZ;
  unsigned short* Wkt = Wqt + WSZ;
  unsigned short* Wvt = Wkt + WSZ;
  unsigned short* Wot = Wvt + WSZ;
  unsigned short* Qb  = Wot + WSZ;
  unsigned short* Kb  = Qb + XSZ;
  unsigned short* Vtb = Kb + XSZ;
  unsigned short* Ob  = Vtb + XSZ;

  cvtbf<<<1024, 256, 0, stream>>>(ctx, Xc, (int)XSZ);
  cvtbf<<<1024, 256, 0, stream>>>(val, Xv, (int)XSZ);
  wtrans<<<dim3(32, 32, 4), dim3(32, 8), 0, stream>>>(Wq, Wk, Wv, Wo, Wqt, Wkt, Wvt, Wot);

  dim3 gg(D_MODEL / 128, BATCH * SEQ / 128);  // (8, 64)
  gemm128<<<gg, 256, 0, stream>>>(Xc, Wqt, bq, Qb, nullptr, 0);
  gemm128<<<gg, 256, 0, stream>>>(Xc, Wkt, bk, Kb, nullptr, 0);
  gemm128<<<gg, 256, 0, stream>>>(Xv, Wvt, bv, Vtb, nullptr, 1);

  attn64<<<dim3(SEQ / 64, BATCH * NH), 256, 0, stream>>>(Qb, Kb, Vtb, Ob);

  gemm128<<<gg, 256, 0, stream>>>(Ob, Wot, bo, nullptr, (float*)d_out, 2);
}

// Round 2
// 258.111 us; speedup vs baseline: 1.6046x; 1.6046x over previous
//
#include <hip/hip_runtime.h>
#include <stdint.h>

#define D_MODEL 1024
#define SEQ 2048
#define BATCH 4
#define NH 16
#define DK 64

typedef float f32x4 __attribute__((ext_vector_type(4)));
typedef __bf16 bf16x8 __attribute__((ext_vector_type(8)));
typedef unsigned short us4v __attribute__((ext_vector_type(4)));

__device__ __forceinline__ unsigned short f2bf(float f) {
  union { float f; unsigned u; } x; x.f = f;
  unsigned r = x.u + 0x7FFFu + ((x.u >> 16) & 1u);  // RNE
  return (unsigned short)(r >> 16);
}

// async global->LDS, 16B per lane. LDS dest is wave-uniform base + lane*16,
// so LDS layout stays linear; swizzling is done on the GLOBAL source address.
__device__ __forceinline__ void gll16(const void* g, void* l) {
  __builtin_amdgcn_global_load_lds(
      (__attribute__((address_space(1))) void*)g,
      (__attribute__((address_space(3))) void*)l, 16, 0, 0);
}

// DPP row_ror:N within 16-lane rows — VALU-speed cross-lane move (no LDS pipe)
template <int CTRL>
__device__ __forceinline__ float dppmv(float x) {
  return __int_as_float(__builtin_amdgcn_update_dpp(
      0, __float_as_int(x), CTRL, 0xf, 0xf, false));
}
// allreduce over each 16-lane row via rotations (commutative ops)
__device__ __forceinline__ float rowmax16(float x) {
  x = fmaxf(x, dppmv<0x128>(x));  // ror:8
  x = fmaxf(x, dppmv<0x124>(x));  // ror:4
  x = fmaxf(x, dppmv<0x122>(x));  // ror:2
  x = fmaxf(x, dppmv<0x121>(x));  // ror:1
  return x;
}
__device__ __forceinline__ float rowsum16(float x) {
  x += dppmv<0x128>(x);
  x += dppmv<0x124>(x);
  x += dppmv<0x122>(x);
  x += dppmv<0x121>(x);
  return x;
}

// ---------------------------------------------------------------------------
// fp32 -> bf16 convert (vectorized float4 -> 4x bf16)
// ---------------------------------------------------------------------------
__global__ void cvtbf(const float* __restrict__ in, unsigned short* __restrict__ out, const int n) {
  const int t = blockIdx.x * blockDim.x + threadIdx.x;
  const int stride = gridDim.x * blockDim.x;
  for (int i = t * 4; i < n; i += stride * 4) {
    const float4 v = *(const float4*)&in[i];
    us4v o;
    o[0] = f2bf(v.x); o[1] = f2bf(v.y); o[2] = f2bf(v.z); o[3] = f2bf(v.w);
    *(us4v*)&out[i] = o;
  }
}

// ---------------------------------------------------------------------------
// weight transpose + convert: W[k][n] fp32 -> Wt[n][k] bf16   (1024x1024, x4)
// ---------------------------------------------------------------------------
__global__ void wtrans(const float* __restrict__ W0, const float* __restrict__ W1,
                       const float* __restrict__ W2, const float* __restrict__ W3,
                       unsigned short* __restrict__ T0, unsigned short* __restrict__ T1,
                       unsigned short* __restrict__ T2, unsigned short* __restrict__ T3) {
  __shared__ float t[32][33];
  const int z = blockIdx.z;
  const float* W = (z == 0) ? W0 : (z == 1) ? W1 : (z == 2) ? W2 : W3;
  unsigned short* T = (z == 0) ? T0 : (z == 1) ? T1 : (z == 2) ? T2 : T3;
  const int n0 = blockIdx.x * 32, k0 = blockIdx.y * 32;
  const int tx = threadIdx.x, ty = threadIdx.y;  // 32 x 8
#pragma unroll
  for (int i = 0; i < 4; ++i)
    t[ty + 8 * i][tx] = W[(size_t)(k0 + ty + 8 * i) * D_MODEL + n0 + tx];
  __syncthreads();
#pragma unroll
  for (int i = 0; i < 4; ++i)
    T[(size_t)(n0 + ty + 8 * i) * D_MODEL + k0 + tx] = f2bf(t[tx][ty + 8 * i]);
}

// ---------------------------------------------------------------------------
// bf16 GEMM: C[M=8192][N=1024] = A[M][K=1024] @ Wt[N][K]^T + bias
// 128x128 tile, BK=64, 4 waves (2x2 of 64x64), mfma_f32_16x16x32_bf16.
// XOR slot-swizzle (slot ^ (row&7)) applied on global source AND ds_read.
// mode 0: out bf16 [b,h,s,d]   (Q, K)
// mode 1: out bf16 [b,h,d,s]   (V transposed for attention PV B-operand)
// mode 2: out fp32 [m][n]      (final projection into d_out)
// ---------------------------------------------------------------------------
__global__ __launch_bounds__(256) void gemm128(
    const unsigned short* __restrict__ A, const unsigned short* __restrict__ Bt,
    const float* __restrict__ bias, unsigned short* __restrict__ outb,
    float* __restrict__ outf, const int mode) {
  __shared__ __align__(16) unsigned short Alds[128 * 64];
  __shared__ __align__(16) unsigned short Blds[128 * 64];
  const int tid = threadIdx.x;
  const int lane = tid & 63;
  const int w = tid >> 6;
  const int wr = w >> 1, wc = w & 1;
  const int m0 = blockIdx.y * 128, n0 = blockIdx.x * 128;
  const int srow = tid >> 3, sslot = tid & 7;

  f32x4 acc[4][4] = {};

  for (int kk = 0; kk < D_MODEL / 64; ++kk) {
    __syncthreads();  // protect LDS from previous iteration's readers
#pragma unroll
    for (int i = 0; i < 4; ++i) {
      const int r = srow + 32 * i;
      const int gc = kk * 64 + ((sslot ^ (r & 7)) << 3);
      gll16(A + (size_t)(m0 + r) * D_MODEL + gc, &Alds[tid * 8 + i * 2048]);
      gll16(Bt + (size_t)(n0 + r) * D_MODEL + gc, &Blds[tid * 8 + i * 2048]);
    }
    __syncthreads();  // compiler drains vmcnt(0) before barrier
#pragma unroll
    for (int kf = 0; kf < 2; ++kf) {
      const int sb = kf * 4 + (lane >> 4);
      bf16x8 a[4], b[4];
#pragma unroll
      for (int m = 0; m < 4; ++m) {
        const int row = wr * 64 + m * 16 + (lane & 15);
        a[m] = *(const bf16x8*)&Alds[row * 64 + ((sb ^ (row & 7)) << 3)];
      }
#pragma unroll
      for (int n = 0; n < 4; ++n) {
        const int row = wc * 64 + n * 16 + (lane & 15);
        b[n] = *(const bf16x8*)&Blds[row * 64 + ((sb ^ (row & 7)) << 3)];
      }
#pragma unroll
      for (int m = 0; m < 4; ++m)
#pragma unroll
        for (int n = 0; n < 4; ++n)
          acc[m][n] = __builtin_amdgcn_mfma_f32_16x16x32_bf16(a[m], b[n], acc[m][n], 0, 0, 0);
    }
  }

  // epilogue: C/D frag layout col = lane&15, row = (lane>>4)*4 + j  [m89]
#pragma unroll
  for (int m = 0; m < 4; ++m) {
    const int rb = m0 + wr * 64 + m * 16 + ((lane >> 4) << 2);
#pragma unroll
    for (int n = 0; n < 4; ++n) {
      const int col = n0 + wc * 64 + n * 16 + (lane & 15);
      const float bv = bias[col];
#pragma unroll
      for (int j = 0; j < 4; ++j) {
        const int row = rb + j;
        const float v = acc[m][n][j] + bv;
        if (mode == 2) {
          outf[(size_t)row * D_MODEL + col] = v;
        } else {
          const int b_ = row >> 11, s_ = row & (SEQ - 1);
          const int h_ = col >> 6, d_ = col & (DK - 1);
          size_t idx;
          if (mode == 0) idx = (((size_t)(b_ * NH + h_)) * SEQ + s_) * DK + d_;
          else           idx = (((size_t)(b_ * NH + h_)) * DK + d_) * SEQ + s_;
          outb[idx] = f2bf(v);
        }
      }
    }
  }
}

// ---------------------------------------------------------------------------
// causal flash attention, balanced + double-buffered.
// Block (pi, bh) processes q-tiles {pi, 31-pi}: total kv-phases = 33 for
// every block (perfect balance). 4 waves x 16 q-rows per 64-row q-tile.
// K [kv][d], Vt [d][kv] double-buffered in swizzled LDS; stage for tile t+1
// issued BEFORE compute of tile t (2-phase pipeline, one barrier per phase).
// Softmax reductions via DPP row_ror (VALU-speed, no LDS pipe).
// ---------------------------------------------------------------------------
__global__ __launch_bounds__(256, 4) void attn64(
    const unsigned short* __restrict__ Q, const unsigned short* __restrict__ K,
    const unsigned short* __restrict__ Vt, unsigned short* __restrict__ O) {
  __shared__ __align__(16) unsigned short Klds[2 * 64 * 64];
  __shared__ __align__(16) unsigned short Vlds[2 * 64 * 64];
  __shared__ __align__(16) unsigned short Plds[4 * 16 * 64];

  const int tid = threadIdx.x, lane = tid & 63, w = tid >> 6;
  const int pi = blockIdx.x, bh = blockIdx.y;
  const size_t qkbase = (size_t)bh * SEQ * DK;
  const size_t vbase = (size_t)bh * DK * SEQ;
  const int srow = tid >> 3, sslot = tid & 7;
  const int b_ = bh >> 4, h_ = bh & (NH - 1);

#pragma unroll
  for (int half = 0; half < 2; ++half) {
    const int qt = half ? (31 - pi) : pi;
    const int q0 = qt * 64;

    // Q fragments (A-operand: row=lane&15, k=(lane>>4)*8+e), pre-scaled by
    // 1/sqrt(DK)=0.125 (power of 2: exact in bf16)
    bf16x8 qf[2];
    {
      const int qrow = q0 + w * 16 + (lane & 15);
      const unsigned short* qp = Q + qkbase + (size_t)qrow * DK + ((lane >> 4) << 3);
      qf[0] = *(const bf16x8*)qp;
      qf[1] = *(const bf16x8*)(qp + 32);
#pragma unroll
      for (int e = 0; e < 8; ++e) {
        qf[0][e] = (__bf16)((float)qf[0][e] * 0.125f);
        qf[1][e] = (__bf16)((float)qf[1][e] * 0.125f);
      }
    }

    float mrow[4] = {-3e38f, -3e38f, -3e38f, -3e38f};
    float lrow[4] = {0.f, 0.f, 0.f, 0.f};
    f32x4 oacc[4] = {};

    // prologue: stage kv-tile 0 into buffer 0
#pragma unroll
    for (int i = 0; i < 2; ++i) {
      const int r = srow + 32 * i;
      const int sc = (sslot ^ (r & 7)) << 3;
      gll16(K + qkbase + (size_t)r * DK + sc, &Klds[tid * 8 + i * 2048]);
      gll16(Vt + vbase + (size_t)r * SEQ + sc, &Vlds[tid * 8 + i * 2048]);
    }
    __syncthreads();

    int cur = 0;
    for (int jt = 0; jt <= qt; ++jt) {
      // issue next tile's stage FIRST — latency hides under compute below
      if (jt < qt) {
        const int nb = cur ^ 1;
#pragma unroll
        for (int i = 0; i < 2; ++i) {
          const int r = srow + 32 * i;
          const int sc = (sslot ^ (r & 7)) << 3;
          gll16(K + qkbase + (size_t)((jt + 1) * 64 + r) * DK + sc,
                &Klds[nb * 4096 + tid * 8 + i * 2048]);
          gll16(Vt + vbase + (size_t)r * SEQ + (jt + 1) * 64 + sc,
                &Vlds[nb * 4096 + tid * 8 + i * 2048]);
        }
      }
      const unsigned short* Kl = &Klds[cur * 4096];
      const unsigned short* Vl = &Vlds[cur * 4096];

      // S = Q K^T : per-wave 16x64 strip
      f32x4 sa[4] = {};
      __builtin_amdgcn_s_setprio(1);
#pragma unroll
      for (int kf = 0; kf < 2; ++kf) {
        const int sb = kf * 4 + (lane >> 4);
#pragma unroll
        for (int n = 0; n < 4; ++n) {
          const int row = n * 16 + (lane & 15);
          const bf16x8 bk = *(const bf16x8*)&Kl[row * 64 + ((sb ^ (row & 7)) << 3)];
          sa[n] = __builtin_amdgcn_mfma_f32_16x16x32_bf16(qf[kf], bk, sa[n], 0, 0, 0);
        }
      }
      __builtin_amdgcn_s_setprio(0);

      const bool diag = (jt == qt);
      float p[4][4];
#pragma unroll
      for (int j = 0; j < 4; ++j) {
        const int qrow = q0 + w * 16 + ((lane >> 4) << 2) + j;
        float mx;
        {
          float s0 = sa[0][j], s1 = sa[1][j], s2 = sa[2][j], s3 = sa[3][j];
          if (diag) {
            const int kc = jt * 64 + (lane & 15);
            if (kc +  0 > qrow) s0 = -3e38f;
            if (kc + 16 > qrow) s1 = -3e38f;
            if (kc + 32 > qrow) s2 = -3e38f;
            if (kc + 48 > qrow) s3 = -3e38f;
          }
          p[0][j] = s0; p[1][j] = s1; p[2][j] = s2; p[3][j] = s3;
          mx = fmaxf(fmaxf(s0, s1), fmaxf(s2, s3));
        }
        mx = rowmax16(mx);
        const float mnew = fmaxf(mrow[j], mx);
        const float alpha = exp2f((mrow[j] - mnew) * 1.44269504f);
        mrow[j] = mnew;
        float rs = 0.f;
#pragma unroll
        for (int n = 0; n < 4; ++n) {
          const float e = exp2f((p[n][j] - mnew) * 1.44269504f);
          p[n][j] = e;
          rs += e;
        }
        rs = rowsum16(rs);
        lrow[j] = lrow[j] * alpha + rs;
#pragma unroll
        for (int dn = 0; dn < 4; ++dn) oacc[dn][j] *= alpha;
      }

      // P (C-frag layout) -> wave-private swizzled LDS -> A-frag layout
      unsigned short* pl = &Plds[w * 16 * 64];
#pragma unroll
      for (int n = 0; n < 4; ++n)
#pragma unroll
        for (int j = 0; j < 4; ++j) {
          const int row = ((lane >> 4) << 2) + j;
          const int col = n * 16 + (lane & 15);
          pl[row * 64 + (((col >> 3) ^ (row & 7)) << 3) + (col & 7)] = f2bf(p[n][j]);
        }

      // O += P @ V   (B-operand from Vt: row d = dn*16 + lane&15, contiguous kv)
      __builtin_amdgcn_s_setprio(1);
#pragma unroll
      for (int kf = 0; kf < 2; ++kf) {
        const int sb = kf * 4 + (lane >> 4);
        const int prow = lane & 15;
        const bf16x8 pa = *(const bf16x8*)&pl[prow * 64 + ((sb ^ (prow & 7)) << 3)];
#pragma unroll
        for (int dn = 0; dn < 4; ++dn) {
          const int vrow = dn * 16 + (lane & 15);
          const bf16x8 bv = *(const bf16x8*)&Vl[vrow * 64 + ((sb ^ (vrow & 7)) << 3)];
          oacc[dn] = __builtin_amdgcn_mfma_f32_16x16x32_bf16(pa, bv, oacc[dn], 0, 0, 0);
        }
      }
      __builtin_amdgcn_s_setprio(0);

      __syncthreads();  // drains staged loads (overlapped) + LDS reader sync
      cur ^= 1;
    }

    // epilogue for this half: O bf16 [b*s][h*64+d]
#pragma unroll
    for (int dn = 0; dn < 4; ++dn) {
      const int col = h_ * DK + dn * 16 + (lane & 15);
#pragma unroll
      for (int j = 0; j < 4; ++j) {
        const int srw = q0 + w * 16 + ((lane >> 4) << 2) + j;
        O[((size_t)(b_ * SEQ + srw)) * D_MODEL + col] = f2bf(oacc[dn][j] / lrow[j]);
      }
    }
    __syncthreads();  // epilogue reads oacc only, but next half re-stages buf0
  }
}

// ---------------------------------------------------------------------------
extern "C" void kernel_launch(void* const* d_in, const int* in_sizes, int n_in,
                              void* d_out, int out_size, void* d_ws, size_t ws_size,
                              hipStream_t stream) {
  const float* ctx = (const float*)d_in[0];
  const float* val = (const float*)d_in[1];
  // d_in[2] = mask: statically causal triu(k=1); handled analytically.
  const float* Wq = (const float*)d_in[3];
  const float* bq = (const float*)d_in[4];
  const float* Wk = (const float*)d_in[5];
  const float* bk = (const float*)d_in[6];
  const float* Wv = (const float*)d_in[7];
  const float* bv = (const float*)d_in[8];
  const float* Wo = (const float*)d_in[9];
  const float* bo = (const float*)d_in[10];

  unsigned short* ws = (unsigned short*)d_ws;
  const size_t XSZ = (size_t)BATCH * SEQ * D_MODEL;  // 8388608
  const size_t WSZ = (size_t)D_MODEL * D_MODEL;      // 1048576
  // total ws use: 6*XSZ + 4*WSZ ushorts = ~109 MB
  unsigned short* Xc  = ws;
  unsigned short* Xv  = Xc + XSZ;
  unsigned short* Wqt = Xv + XSZ;
  unsigned short* Wkt = Wqt + WSZ;
  unsigned short* Wvt = Wkt + WSZ;
  unsigned short* Wot = Wvt + WSZ;
  unsigned short* Qb  = Wot + WSZ;
  unsigned short* Kb  = Qb + XSZ;
  unsigned short* Vtb = Kb + XSZ;
  unsigned short* Ob  = Vtb + XSZ;

  cvtbf<<<1024, 256, 0, stream>>>(ctx, Xc, (int)XSZ);
  cvtbf<<<1024, 256, 0, stream>>>(val, Xv, (int)XSZ);
  wtrans<<<dim3(32, 32, 4), dim3(32, 8), 0, stream>>>(Wq, Wk, Wv, Wo, Wqt, Wkt, Wvt, Wot);

  dim3 gg(D_MODEL / 128, BATCH * SEQ / 128);  // (8, 64)
  gemm128<<<gg, 256, 0, stream>>>(Xc, Wqt, bq, Qb, nullptr, 0);
  gemm128<<<gg, 256, 0, stream>>>(Xc, Wkt, bk, Kb, nullptr, 0);
  gemm128<<<gg, 256, 0, stream>>>(Xv, Wvt, bv, Vtb, nullptr, 1);

  attn64<<<dim3(16, BATCH * NH), 256, 0, stream>>>(Qb, Kb, Vtb, Ob);

  gemm128<<<gg, 256, 0, stream>>>(Ob, Wot, bo, nullptr, (float*)d_out, 2);
}

// Round 3
// 227.763 us; speedup vs baseline: 1.8184x; 1.1332x over previous
//
#include <hip/hip_runtime.h>
#include <stdint.h>

#define D_MODEL 1024
#define SEQ 2048
#define BATCH 4
#define NH 16
#define DK 64

typedef float f32x4 __attribute__((ext_vector_type(4)));
typedef float f32x16 __attribute__((ext_vector_type(16)));
typedef __bf16 bf16x8 __attribute__((ext_vector_type(8)));
typedef unsigned short us4v __attribute__((ext_vector_type(4)));

__device__ __forceinline__ unsigned short f2bf(float f) {
  union { float f; unsigned u; } x; x.f = f;
  unsigned r = x.u + 0x7FFFu + ((x.u >> 16) & 1u);  // RNE
  return (unsigned short)(r >> 16);
}

// async global->LDS, 16B per lane. LDS dest is wave-uniform base + lane*16,
// so LDS layout stays linear; swizzling is done on the GLOBAL source address.
__device__ __forceinline__ void gll16(const void* g, void* l) {
  __builtin_amdgcn_global_load_lds(
      (__attribute__((address_space(1))) void*)g,
      (__attribute__((address_space(3))) void*)l, 16, 0, 0);
}

// packed f32x2 -> bf16x2 (RNE), one VALU op
__device__ __forceinline__ int cvtpk(float lo, float hi) {
  int r;
  asm("v_cvt_pk_bf16_f32 %0, %1, %2" : "=v"(r) : "v"(lo), "v"(hi));
  return r;
}
// v_permlane32_swap_b32: a[32:63] <-> b[0:31].
// After: a = {a.low | b.low-from-partner}, b = {a.high-from-partner | b.high}
__device__ __forceinline__ void pl32swap(int& a, int& b) {
  asm volatile("v_permlane32_swap_b32 %0, %1" : "+v"(a), "+v"(b));
}

// ---------------------------------------------------------------------------
// fp32 -> bf16 convert (vectorized float4 -> 4x bf16)
// ---------------------------------------------------------------------------
__global__ void cvtbf(const float* __restrict__ in, unsigned short* __restrict__ out, const int n) {
  const int t = blockIdx.x * blockDim.x + threadIdx.x;
  const int stride = gridDim.x * blockDim.x;
  for (int i = t * 4; i < n; i += stride * 4) {
    const float4 v = *(const float4*)&in[i];
    us4v o;
    o[0] = f2bf(v.x); o[1] = f2bf(v.y); o[2] = f2bf(v.z); o[3] = f2bf(v.w);
    *(us4v*)&out[i] = o;
  }
}

// ---------------------------------------------------------------------------
// weight transpose + convert: W[k][n] fp32 -> Wt[n][k] bf16   (1024x1024, x4)
// ---------------------------------------------------------------------------
__global__ void wtrans(const float* __restrict__ W0, const float* __restrict__ W1,
                       const float* __restrict__ W2, const float* __restrict__ W3,
                       unsigned short* __restrict__ T0, unsigned short* __restrict__ T1,
                       unsigned short* __restrict__ T2, unsigned short* __restrict__ T3) {
  __shared__ float t[32][33];
  const int z = blockIdx.z;
  const float* W = (z == 0) ? W0 : (z == 1) ? W1 : (z == 2) ? W2 : W3;
  unsigned short* T = (z == 0) ? T0 : (z == 1) ? T1 : (z == 2) ? T2 : T3;
  const int n0 = blockIdx.x * 32, k0 = blockIdx.y * 32;
  const int tx = threadIdx.x, ty = threadIdx.y;  // 32 x 8
#pragma unroll
  for (int i = 0; i < 4; ++i)
    t[ty + 8 * i][tx] = W[(size_t)(k0 + ty + 8 * i) * D_MODEL + n0 + tx];
  __syncthreads();
#pragma unroll
  for (int i = 0; i < 4; ++i)
    T[(size_t)(n0 + ty + 8 * i) * D_MODEL + k0 + tx] = f2bf(t[tx][ty + 8 * i]);
}

// ---------------------------------------------------------------------------
// bf16 GEMM: C[M=8192][N=1024] = A[M][K=1024] @ Wt[N][K]^T + bias
// 128x128 tile, BK=64, 4 waves (2x2 of 64x64), mfma_f32_16x16x32_bf16.
// mode 0: out bf16 [b,h,s,d] (Q,K); mode 1: out bf16 [b,h,d,s] (V^T);
// mode 2: out fp32 [m][n] (final projection)
// ---------------------------------------------------------------------------
__global__ __launch_bounds__(256) void gemm128(
    const unsigned short* __restrict__ A, const unsigned short* __restrict__ Bt,
    const float* __restrict__ bias, unsigned short* __restrict__ outb,
    float* __restrict__ outf, const int mode) {
  __shared__ __align__(16) unsigned short Alds[128 * 64];
  __shared__ __align__(16) unsigned short Blds[128 * 64];
  const int tid = threadIdx.x;
  const int lane = tid & 63;
  const int w = tid >> 6;
  const int wr = w >> 1, wc = w & 1;
  const int m0 = blockIdx.y * 128, n0 = blockIdx.x * 128;
  const int srow = tid >> 3, sslot = tid & 7;

  f32x4 acc[4][4] = {};

  for (int kk = 0; kk < D_MODEL / 64; ++kk) {
    __syncthreads();
#pragma unroll
    for (int i = 0; i < 4; ++i) {
      const int r = srow + 32 * i;
      const int gc = kk * 64 + ((sslot ^ (r & 7)) << 3);
      gll16(A + (size_t)(m0 + r) * D_MODEL + gc, &Alds[tid * 8 + i * 2048]);
      gll16(Bt + (size_t)(n0 + r) * D_MODEL + gc, &Blds[tid * 8 + i * 2048]);
    }
    __syncthreads();
#pragma unroll
    for (int kf = 0; kf < 2; ++kf) {
      const int sb = kf * 4 + (lane >> 4);
      bf16x8 a[4], b[4];
#pragma unroll
      for (int m = 0; m < 4; ++m) {
        const int row = wr * 64 + m * 16 + (lane & 15);
        a[m] = *(const bf16x8*)&Alds[row * 64 + ((sb ^ (row & 7)) << 3)];
      }
#pragma unroll
      for (int n = 0; n < 4; ++n) {
        const int row = wc * 64 + n * 16 + (lane & 15);
        b[n] = *(const bf16x8*)&Blds[row * 64 + ((sb ^ (row & 7)) << 3)];
      }
#pragma unroll
      for (int m = 0; m < 4; ++m)
#pragma unroll
        for (int n = 0; n < 4; ++n)
          acc[m][n] = __builtin_amdgcn_mfma_f32_16x16x32_bf16(a[m], b[n], acc[m][n], 0, 0, 0);
    }
  }

#pragma unroll
  for (int m = 0; m < 4; ++m) {
    const int rb = m0 + wr * 64 + m * 16 + ((lane >> 4) << 2);
#pragma unroll
    for (int n = 0; n < 4; ++n) {
      const int col = n0 + wc * 64 + n * 16 + (lane & 15);
      const float bv = bias[col];
#pragma unroll
      for (int j = 0; j < 4; ++j) {
        const int row = rb + j;
        const float v = acc[m][n][j] + bv;
        if (mode == 2) {
          outf[(size_t)row * D_MODEL + col] = v;
        } else {
          const int b_ = row >> 11, s_ = row & (SEQ - 1);
          const int h_ = col >> 6, d_ = col & (DK - 1);
          size_t idx;
          if (mode == 0) idx = (((size_t)(b_ * NH + h_)) * SEQ + s_) * DK + d_;
          else           idx = (((size_t)(b_ * NH + h_)) * DK + d_) * SEQ + s_;
          outb[idx] = f2bf(v);
        }
      }
    }
  }
}

// ---------------------------------------------------------------------------
// causal flash attention, swapped-QK^T (T12) 32x32x16 structure.
// Block (pi, bh) does q-tiles {pi, 15-pi} of 128 rows; 4 waves x 32 q-rows.
// Per wave: S^T[kv][q] = K·Q^T so each lane owns one q-row of P in regs.
// Softmax: lane-local trees + one shfl_xor(32). P->bf16 B-frag via
// cvt_pk + permlane32_swap (no LDS round trip). PV swapped: O^T = V^T·P^T.
// K [kv][d], Vt [d][kv] double-buffered swizzled LDS; defer-max THR=8.
// ---------------------------------------------------------------------------
__global__ __launch_bounds__(256, 2) void attn32s(
    const unsigned short* __restrict__ Q, const unsigned short* __restrict__ K,
    const unsigned short* __restrict__ Vt, unsigned short* __restrict__ O) {
  __shared__ __align__(16) unsigned short Klds[2 * 64 * 64];
  __shared__ __align__(16) unsigned short Vlds[2 * 64 * 64];

  const int tid = threadIdx.x, lane = tid & 63, w = tid >> 6;
  const int lq = lane & 31, hi = lane >> 5;
  const int pi = blockIdx.x, bh = blockIdx.y;
  const size_t qkbase = (size_t)bh * SEQ * DK;
  const size_t vbase = (size_t)bh * DK * SEQ;
  const int srow = tid >> 3, sslot = tid & 7;
  const int b_ = bh >> 4, h_ = bh & (NH - 1);

#pragma unroll
  for (int half = 0; half < 2; ++half) {
    const int qt = half ? (15 - pi) : pi;
    const int q0 = qt * 128;
    const int qw0 = q0 + w * 32;       // wave's first q-row
    const int qg = qw0 + lq;           // this lane's q-row

    // Q as B-operand frags: col=lane&31 -> q, k=(lane>>5)*8+e per 16-slice.
    // Pre-scaled by 1/sqrt(DK)=0.125 (power of 2 -> exact in bf16).
    bf16x8 qb[4];
    {
      const unsigned short* qp = Q + qkbase + (size_t)qg * DK + hi * 8;
#pragma unroll
      for (int ks = 0; ks < 4; ++ks) {
        qb[ks] = *(const bf16x8*)(qp + ks * 16);
#pragma unroll
        for (int e = 0; e < 8; ++e)
          qb[ks][e] = (__bf16)((float)qb[ks][e] * 0.125f);
      }
    }

    float m = -3e38f, l = 0.f;
    f32x16 o0 = {}, o1 = {};

    // prologue: stage kv-tile 0 into buffer 0
#pragma unroll
    for (int i = 0; i < 2; ++i) {
      const int r = srow + 32 * i;
      const int sc = (sslot ^ (r & 7)) << 3;
      gll16(K + qkbase + (size_t)r * DK + sc, &Klds[tid * 8 + i * 2048]);
      gll16(Vt + vbase + (size_t)r * SEQ + sc, &Vlds[tid * 8 + i * 2048]);
    }
    __syncthreads();

    const int nphase = 2 * qt + 2;
    int cur = 0;
    for (int jt = 0; jt < nphase; ++jt) {
      // stage next tile first — latency hides under compute
      if (jt + 1 < nphase) {
        const int nb = cur ^ 1;
#pragma unroll
        for (int i = 0; i < 2; ++i) {
          const int r = srow + 32 * i;
          const int sc = (sslot ^ (r & 7)) << 3;
          gll16(K + qkbase + (size_t)((jt + 1) * 64 + r) * DK + sc,
                &Klds[nb * 4096 + tid * 8 + i * 2048]);
          gll16(Vt + vbase + (size_t)r * SEQ + (jt + 1) * 64 + sc,
                &Vlds[nb * 4096 + tid * 8 + i * 2048]);
        }
      }

      // wave skips fully-masked phases (still participates in barrier)
      if (64 * jt < qw0 + 32) {
        const unsigned short* Kl = &Klds[cur * 4096];
        const unsigned short* Vl = &Vlds[cur * 4096];

        // S^T = K·Q^T : st0 = kv 0..31, st1 = kv 32..63 (cols = 32 q's)
        f32x16 st0 = {}, st1 = {};
        __builtin_amdgcn_s_setprio(1);
#pragma unroll
        for (int ks = 0; ks < 4; ++ks) {
          const int so = ((ks * 2 + hi) ^ (lq & 7)) << 3;
          const bf16x8 ka0 = *(const bf16x8*)&Kl[lq * 64 + so];
          const bf16x8 ka1 = *(const bf16x8*)&Kl[(32 + lq) * 64 + so];
          st0 = __builtin_amdgcn_mfma_f32_32x32x16_bf16(ka0, qb[ks], st0, 0, 0, 0);
          st1 = __builtin_amdgcn_mfma_f32_32x32x16_bf16(ka1, qb[ks], st1, 0, 0, 0);
        }
        __builtin_amdgcn_s_setprio(0);

        // causal mask: kv = 64*jt + kvb*32 + (reg&3)+8*(reg>>2)+4*hi  > qg
        if (64 * jt + 63 > qw0) {
          const int rb = 64 * jt + 4 * hi - qg;
#pragma unroll
          for (int r = 0; r < 16; ++r) {
            const int crow0 = (r & 3) + 8 * (r >> 2);
            if (crow0 + rb > 0)      st0[r] = -3e38f;
            if (crow0 + 32 + rb > 0) st1[r] = -3e38f;
          }
        }

        // row max: lane-local tree + one cross-half exchange
        float tmax[8];
#pragma unroll
        for (int r = 0; r < 8; ++r)
          tmax[r] = fmaxf(fmaxf(st0[r], st0[r + 8]), fmaxf(st1[r], st1[r + 8]));
        float mx = fmaxf(fmaxf(fmaxf(tmax[0], tmax[1]), fmaxf(tmax[2], tmax[3])),
                         fmaxf(fmaxf(tmax[4], tmax[5]), fmaxf(tmax[6], tmax[7])));
        mx = fmaxf(mx, __shfl_xor(mx, 32));

        // defer-max (T13, THR=8): skip rescale when max barely grew
        if (__any((int)(mx > m + 8.0f))) {
          const float mnew = fmaxf(m, mx);
          const float alpha = exp2f((m - mnew) * 1.44269504f);
          m = mnew;
          l *= alpha;
#pragma unroll
          for (int r = 0; r < 16; ++r) { o0[r] *= alpha; o1[r] *= alpha; }
        }

        // exp (P kept in st regs, bounded by e^8 under defer)
        const float ml = m * 1.44269504f;
#pragma unroll
        for (int r = 0; r < 16; ++r) {
          st0[r] = exp2f(__builtin_fmaf(st0[r], 1.44269504f, -ml));
          st1[r] = exp2f(__builtin_fmaf(st1[r], 1.44269504f, -ml));
        }

        // row sum: tree + cross-half
        float tsum[8];
#pragma unroll
        for (int r = 0; r < 8; ++r)
          tsum[r] = (st0[r] + st0[r + 8]) + (st1[r] + st1[r + 8]);
        float rs = ((tsum[0] + tsum[1]) + (tsum[2] + tsum[3])) +
                   ((tsum[4] + tsum[5]) + (tsum[6] + tsum[7]));
        rs += __shfl_xor(rs, 32);
        l += rs;

        // P -> bf16 B-frags via cvt_pk + permlane32_swap (T12)
        bf16x8 pb[4];
#pragma unroll
        for (int ks = 0; ks < 4; ++ks) {
          const int base = (ks & 1) * 8;
          float p0, p1, p2, p3, p4, p5, p6, p7;
          if (ks < 2) {
            p0 = st0[base + 0]; p1 = st0[base + 1]; p2 = st0[base + 2]; p3 = st0[base + 3];
            p4 = st0[base + 4]; p5 = st0[base + 5]; p6 = st0[base + 6]; p7 = st0[base + 7];
          } else {
            p0 = st1[base + 0]; p1 = st1[base + 1]; p2 = st1[base + 2]; p3 = st1[base + 3];
            p4 = st1[base + 4]; p5 = st1[base + 5]; p6 = st1[base + 6]; p7 = st1[base + 7];
          }
          int a0 = cvtpk(p0, p1), a1 = cvtpk(p2, p3);
          int a2 = cvtpk(p4, p5), a3 = cvtpk(p6, p7);
          pl32swap(a0, a2);   // a0 -> B word0, a2 -> B word2
          pl32swap(a1, a3);   // a1 -> B word1, a3 -> B word3
          union { int i[4]; bf16x8 v; } u;
          u.i[0] = a0; u.i[1] = a1; u.i[2] = a2; u.i[3] = a3;
          pb[ks] = u.v;
        }

        // O^T += V^T·P^T : A = Vt rows (d), B = pb
        __builtin_amdgcn_s_setprio(1);
#pragma unroll
        for (int ks = 0; ks < 4; ++ks) {
          const int so = ((ks * 2 + hi) ^ (lq & 7)) << 3;
          const bf16x8 va0 = *(const bf16x8*)&Vl[lq * 64 + so];
          const bf16x8 va1 = *(const bf16x8*)&Vl[(32 + lq) * 64 + so];
          o0 = __builtin_amdgcn_mfma_f32_32x32x16_bf16(va0, pb[ks], o0, 0, 0, 0);
          o1 = __builtin_amdgcn_mfma_f32_32x32x16_bf16(va1, pb[ks], o1, 0, 0, 0);
        }
        __builtin_amdgcn_s_setprio(0);
      }

      __syncthreads();  // drains staged loads + LDS reader sync
      cur ^= 1;
    }

    // epilogue: O[b*s][h*64+d]; lane owns q-row qg, rows of o are d.
    // d = db*32 + 8*g + 4*hi + (reg&3): 4 consecutive -> 8B packed stores.
    const float rl = 1.0f / l;
    unsigned short* orow = O + (size_t)(b_ * SEQ + qg) * D_MODEL + h_ * DK;
#pragma unroll
    for (int g = 0; g < 4; ++g) {
      us4v pk0, pk1;
#pragma unroll
      for (int j = 0; j < 4; ++j) {
        pk0[j] = f2bf(o0[4 * g + j] * rl);
        pk1[j] = f2bf(o1[4 * g + j] * rl);
      }
      const int d0 = 8 * g + 4 * hi;
      *(us4v*)&orow[d0] = pk0;
      *(us4v*)&orow[32 + d0] = pk1;
    }
    __syncthreads();  // next half restages buf0; keep waves together
  }
}

// ---------------------------------------------------------------------------
extern "C" void kernel_launch(void* const* d_in, const int* in_sizes, int n_in,
                              void* d_out, int out_size, void* d_ws, size_t ws_size,
                              hipStream_t stream) {
  const float* ctx = (const float*)d_in[0];
  const float* val = (const float*)d_in[1];
  // d_in[2] = mask: statically causal triu(k=1); handled analytically.
  const float* Wq = (const float*)d_in[3];
  const float* bq = (const float*)d_in[4];
  const float* Wk = (const float*)d_in[5];
  const float* bk = (const float*)d_in[6];
  const float* Wv = (const float*)d_in[7];
  const float* bv = (const float*)d_in[8];
  const float* Wo = (const float*)d_in[9];
  const float* bo = (const float*)d_in[10];

  unsigned short* ws = (unsigned short*)d_ws;
  const size_t XSZ = (size_t)BATCH * SEQ * D_MODEL;  // 8388608
  const size_t WSZ = (size_t)D_MODEL * D_MODEL;      // 1048576
  unsigned short* Xc  = ws;
  unsigned short* Xv  = Xc + XSZ;
  unsigned short* Wqt = Xv + XSZ;
  unsigned short* Wkt = Wqt + WSZ;
  unsigned short* Wvt = Wkt + WSZ;
  unsigned short* Wot = Wvt + WSZ;
  unsigned short* Qb  = Wot + WSZ;
  unsigned short* Kb  = Qb + XSZ;
  unsigned short* Vtb = Kb + XSZ;
  unsigned short* Ob  = Vtb + XSZ;

  cvtbf<<<1024, 256, 0, stream>>>(ctx, Xc, (int)XSZ);
  cvtbf<<<1024, 256, 0, stream>>>(val, Xv, (int)XSZ);
  wtrans<<<dim3(32, 32, 4), dim3(32, 8), 0, stream>>>(Wq, Wk, Wv, Wo, Wqt, Wkt, Wvt, Wot);

  dim3 gg(D_MODEL / 128, BATCH * SEQ / 128);  // (8, 64)
  gemm128<<<gg, 256, 0, stream>>>(Xc, Wqt, bq, Qb, nullptr, 0);
  gemm128<<<gg, 256, 0, stream>>>(Xc, Wkt, bk, Kb, nullptr, 0);
  gemm128<<<gg, 256, 0, stream>>>(Xv, Wvt, bv, Vtb, nullptr, 1);

  attn32s<<<dim3(8, BATCH * NH), 256, 0, stream>>>(Qb, Kb, Vtb, Ob);

  gemm128<<<gg, 256, 0, stream>>>(Ob, Wot, bo, nullptr, (float*)d_out, 2);
}